// Round 3
// baseline (327.537 us; speedup 1.0000x reference)
//
#include <hip/hip_runtime.h>
#include <hip/hip_bf16.h>
#include <cstdint>

#define BATCH 32
#define NITEMS 16384
#define DEMB 128
#define IDIM 64

typedef short short8 __attribute__((ext_vector_type(8)));
typedef float f32x4 __attribute__((ext_vector_type(4)));

// ---------- helpers ----------
__device__ inline unsigned short f2bf(float f) {
    union { float f; unsigned int u; } v; v.f = f;
    unsigned int u = v.u;
    unsigned int r = (u + 0x7FFFu + ((u >> 16) & 1u)) >> 16;   // RNE, data is finite
    return (unsigned short)r;
}
__device__ inline float bf2f(unsigned short h) {
    union { unsigned int u; float f; } v; v.u = ((unsigned int)h) << 16;
    return v.f;
}

// Exact-erf gelu via A&S 7.1.26 (|erf err| <= 1.5e-7), restructured:
// q = 0.5*(1-erf(|x|/sqrt2)) = P2(t)*exp2(-x^2*log2(e)/2), t = 1/(1+0.32759*|x|/sqrt2)
// gelu = x * (x>0 ? 1-q : q).  2 trans-pipe ops (rcp, exp2) co-issue with fma.
__device__ inline float gelu_f(float x) {
    float y = fabsf(x) * 0.70710678118654752f;
    float t = __builtin_amdgcn_rcpf(fmaf(0.3275911f, y, 1.0f));
    float p = fmaf(0.5307027145f, t, -0.7265760135f);     // a5/2, a4/2
    p = fmaf(p, t, 0.7107068705f);                        // a3/2
    p = fmaf(p, t, -0.142248368f);                        // a2/2
    p = fmaf(p, t, 0.127414796f);                         // a1/2
    p = p * t;
    float e = __builtin_amdgcn_exp2f(x * x * -0.72134752044448171f);
    float q = p * e;                                      // 0.5*erfc(y)
    float phi = (x > 0.f) ? (1.0f - q) : q;
    return x * phi;
}

// ---------- kernel 0: query path -> r[b] ; split-bf16 weight prep ; ctr zero ----------
__global__ __launch_bounds__(128) void k0_prep(
    const float* __restrict__ xq, const float* __restrict__ wq1, const float* __restrict__ bq1,
    const float* __restrict__ wq2, const float* __restrict__ bq2,
    const float* __restrict__ wqp, const float* __restrict__ bqp,
    const float* __restrict__ wkp,
    const float* __restrict__ wx1, const float* __restrict__ wx2,
    float* __restrict__ r_out, unsigned short* __restrict__ w1h, unsigned short* __restrict__ w1l,
    int* __restrict__ ctr) {
    __shared__ float buf1[128], buf2[128], buf3[128], buf4[128];
    int t = threadIdx.x;
    int blk = blockIdx.x;
    if (blk < BATCH) {
        int b = blk;
        float xqv = xq[b];
        buf1[t] = gelu_f(fmaf(xqv, wq1[t], bq1[t]));
        __syncthreads();
        float acc = bq2[t];
        for (int j = 0; j < 128; j++) acc = fmaf(buf1[j], wq2[j * 128 + t], acc);
        buf2[t] = acc;
        __syncthreads();
        acc = bqp[t];
        for (int j = 0; j < 128; j++) acc = fmaf(buf2[j], wqp[j * 128 + t], acc);
        buf3[t] = acc;                       // q[b]
        __syncthreads();
        acc = 0.f;
        for (int i = 0; i < 128; i++) acc = fmaf(wkp[t * 128 + i], buf3[i], acc);
        buf4[t] = acc * 0.08838834764831845f; // qt = (wkp @ q) * 128^-0.5
        __syncthreads();
        acc = 0.f;
        for (int i = 0; i < 128; i++) acc = fmaf(wx2[t * 128 + i], buf4[i], acc);
        r_out[b * 128 + t] = acc;            // r = wx2 @ qt  (score[n] = h1g[n] . r[b] + const)
    } else {
        if (t < BATCH) ctr[t] = 0;           // support-list counters (workspace is poisoned)
        // wx1 [64][128] -> w1h/w1l [n=128][k=64] bf16 hi/lo split
        for (int idx = t; idx < 64 * 128; idx += 128) {
            int k = idx >> 7, n = idx & 127;
            float v = wx1[idx];
            unsigned short hi = f2bf(v);
            float lo = v - bf2f(hi);
            w1h[n * 64 + k] = hi;
            w1l[n * 64 + k] = f2bf(lo);
        }
    }
}

// ---------- kernel 1: per-item GEMM1 (split-bf16 MFMA) + gelu + score dot ----------
// TRANSPOSED: C = W1 (A, M=128 n-dims) x X^T (B, N=64 items), K=64.
// C rows = h1-dims, C cols = items -> score dot over n-dims is per-lane FMA +
// 2-step quad shuffle (8 DS ops) instead of a 4-step 16-lane butterfly (64).
// 64 items per block, 256 threads = 4 waves; wave owns 32 rows (2 m-tiles).
__global__ __launch_bounds__(256) void k1_items(
    const float* __restrict__ x, const unsigned short* __restrict__ w1h,
    const unsigned short* __restrict__ w1l, const float* __restrict__ bx1,
    const float* __restrict__ r_in, float* __restrict__ scores) {
    __shared__ alignas(16) unsigned short lxh[64 * 72];
    __shared__ alignas(16) unsigned short lxl[64 * 72];
    __shared__ float red[4][64];
    int tid = threadIdx.x;
    int wave = tid >> 6, lane = tid & 63;
    int quad = lane >> 4, l15 = lane & 15;
    int tile = blockIdx.x;
    long item0 = (long)tile * 64;
    int b = tile >> 8;                       // 256 tiles per batch

    // resident A fragments = weights: rows wave*32 + mt*16 + l15, k-contig
    short8 wh[2][2], wl[2][2];               // [s][mt]
    for (int s = 0; s < 2; s++)
        for (int mt = 0; mt < 2; mt++) {
            int off = (wave * 32 + mt * 16 + l15) * 64 + s * 32 + quad * 8;
            wh[s][mt] = *(const short8*)(w1h + off);
            wl[s][mt] = *(const short8*)(w1l + off);
        }
    // per-lane row constants: row = wave*32 + mt*16 + quad*4 + rr
    float bias8[2][4], rv8[2][4];
    for (int mt = 0; mt < 2; mt++)
        for (int rr = 0; rr < 4; rr++) {
            int row = wave * 32 + mt * 16 + quad * 4 + rr;
            bias8[mt][rr] = bx1[row];
            rv8[mt][rr] = r_in[b * 128 + row];
        }

    // stage x tile [64 items x 64 k]: trunc hi/lo bf16 split via v_perm packing
    const float* xg = x + item0 * 64;
    for (int p = 0; p < 4; p++) {
        int idx = tid + p * 256;
        int row = idx >> 4, c4 = (idx & 15) * 4;
        float4 v = *(const float4*)(xg + row * 64 + c4);
        unsigned int ux = __float_as_uint(v.x), uy = __float_as_uint(v.y);
        unsigned int uz = __float_as_uint(v.z), uw = __float_as_uint(v.w);
        unsigned int hi01 = __builtin_amdgcn_perm(uy, ux, 0x07060302u);
        unsigned int hi23 = __builtin_amdgcn_perm(uw, uz, 0x07060302u);
        float lx = v.x - __uint_as_float(ux & 0xFFFF0000u);
        float ly = v.y - __uint_as_float(uy & 0xFFFF0000u);
        float lz = v.z - __uint_as_float(uz & 0xFFFF0000u);
        float lw = v.w - __uint_as_float(uw & 0xFFFF0000u);
        unsigned int lo01 = __builtin_amdgcn_perm(__float_as_uint(ly), __float_as_uint(lx), 0x07060302u);
        unsigned int lo23 = __builtin_amdgcn_perm(__float_as_uint(lw), __float_as_uint(lz), 0x07060302u);
        *(uint2*)(lxh + row * 72 + c4) = make_uint2(hi01, hi23);
        *(uint2*)(lxl + row * 72 + c4) = make_uint2(lo01, lo23);
    }
    __syncthreads();

    // acc init = bias (row-wise constant, folded into MFMA C)
    f32x4 acc[2][4];                         // [mt][nt]
    for (int mt = 0; mt < 2; mt++)
        for (int nt = 0; nt < 4; nt++) {
            f32x4 bi = {bias8[mt][0], bias8[mt][1], bias8[mt][2], bias8[mt][3]};
            acc[mt][nt] = bi;
        }

    for (int s = 0; s < 2; s++) {
        int koff = s * 32 + quad * 8;
        short8 xh[4], xl[4];                 // B fragments: col = nt*16 + l15
        for (int nt = 0; nt < 4; nt++) {
            int rb = (nt * 16 + l15) * 72 + koff;
            xh[nt] = *(const short8*)(lxh + rb);
            xl[nt] = *(const short8*)(lxl + rb);
        }
        for (int mt = 0; mt < 2; mt++)
            for (int nt = 0; nt < 4; nt++) {
                acc[mt][nt] = __builtin_amdgcn_mfma_f32_16x16x32_bf16(wh[s][mt], xl[nt], acc[mt][nt], 0, 0, 0);
                acc[mt][nt] = __builtin_amdgcn_mfma_f32_16x16x32_bf16(wl[s][mt], xh[nt], acc[mt][nt], 0, 0, 0);
                acc[mt][nt] = __builtin_amdgcn_mfma_f32_16x16x32_bf16(wh[s][mt], xh[nt], acc[mt][nt], 0, 0, 0);
            }
    }

    // epilogue: gelu + dot with r over rows (per-lane), reduce over quad axis
    float pr[4] = {0.f, 0.f, 0.f, 0.f};      // per nt -> item nt*16 + l15
    for (int mt = 0; mt < 2; mt++)
        for (int nt = 0; nt < 4; nt++)
            for (int rr = 0; rr < 4; rr++) {
                float g = gelu_f(acc[mt][nt][rr]);
                pr[nt] = fmaf(g, rv8[mt][rr], pr[nt]);
            }
    for (int nt = 0; nt < 4; nt++) {
        pr[nt] += __shfl_xor(pr[nt], 16);
        pr[nt] += __shfl_xor(pr[nt], 32);
    }
    if (quad == 0)
        for (int nt = 0; nt < 4; nt++)
            red[wave][nt * 16 + l15] = pr[nt];
    __syncthreads();
    if (tid < 64)
        scores[item0 + tid] = red[0][tid] + red[1][tid] + red[2][tid] + red[3][tid];
}

// ---------- kernel 2: sparsemax tau (Michelot, early exit) + support compaction ----------
// Iteration 0 with tau=-1e30 reproduces the classic init (tau=(sum-1)/N) bit-exactly.
// Early exit when tau repeats bit-exactly (fixed point; uniform branch).
// After convergence every thread still holds its 16 z values -> emit the compact
// support list (index, weight=z-tau) with ballot-aggregated atomics: at most one
// atomic per wave per slot, zero when the wave has no hits (common case).
__global__ __launch_bounds__(1024) void k2_tau(const float* __restrict__ scores,
                                               float* __restrict__ tau_out,
                                               float* __restrict__ u,
                                               int* __restrict__ ctr,
                                               int* __restrict__ sidx,
                                               float* __restrict__ swgt) {
    __shared__ float la[2][16], lc[2][16];
    int b = blockIdx.x, t = threadIdx.x;
    int wid = t >> 6, lane = t & 63;
    const float* s = scores + (size_t)b * NITEMS;
    float z[16];
    for (int i = 0; i < 16; i++) z[i] = s[t + i * 1024];
    float tau = -1e30f;
    for (int it = 0; it < 21; it++) {
        int pb = it & 1;
        float ls = 0.f, ct = 0.f;
        for (int i = 0; i < 16; i++) {
            bool a = z[i] > tau;
            ls += a ? z[i] : 0.f;
            ct += a ? 1.f : 0.f;
        }
        for (int off = 32; off; off >>= 1) {
            ls += __shfl_xor(ls, off);
            ct += __shfl_xor(ct, off);
        }
        if (lane == 0) { la[pb][wid] = ls; lc[pb][wid] = ct; }
        __syncthreads();
        float tls = 0.f, tct = 0.f;
        for (int i = 0; i < 16; i++) { tls += la[pb][i]; tct += lc[pb][i]; }
        float ntau = (tls - 1.0f) / tct;     // ct >= 1 always (max > tau)
        if (ntau == tau) break;              // fixed point reached (uniform)
        tau = ntau;
    }
    if (t == 0) tau_out[b] = tau;
    if (t < 128) u[b * 128 + t] = 0.f;

    // ---- compaction: support = { z > tau }, weight = z - tau (bit-identical
    // to the old k3's srow[..] - tau; same loads, same subtraction) ----
    size_t lbase = (size_t)b * NITEMS;
    for (int i = 0; i < 16; i++) {
        bool hit = z[i] > tau;
        unsigned long long m = __ballot(hit);
        if (m) {
            int base = 0;
            if (lane == 0) base = atomicAdd(&ctr[b], (int)__popcll(m));
            base = __shfl(base, 0);
            if (hit) {
                int off = __popcll(m & ((1ULL << lane) - 1ULL));
                sidx[lbase + base + off] = t + i * 1024;
                swgt[lbase + base + off] = z[i] - tau;
            }
        }
    }
}

// ---------- kernel 3: balanced support recompute from compact list ----------
// Waves pull items round-robin from the per-batch compact list: perfect load
// balance (old version: each wave owned a fixed 128-item slice -> duration set
// by the Poisson-max wave, plus a full 2 MB score rescan). fp32 math unchanged.
// No fences / tickets (round-1 lesson: +58.7 us L2 writeback storm).
__global__ __launch_bounds__(256) void k3_support(
    const int* __restrict__ ctr, const int* __restrict__ sidx,
    const float* __restrict__ swgt, const float* __restrict__ x,
    const float* __restrict__ wx1, const float* __restrict__ bx1,
    const float* __restrict__ wx2, const float* __restrict__ bx2,
    float* __restrict__ u) {
    __shared__ float red[4][128];
    int blk = blockIdx.x;
    int b = blk >> 5;                 // 32 blocks per batch
    int sub = blk & 31;
    int wave = threadIdx.x >> 6, lane = threadIdx.x & 63;
    int wslot = sub * 4 + wave;       // 0..127 within batch
    int cnt = ctr[b];
    int t0 = lane, t1 = lane + 64;
    float bb0 = bx1[t0], bb1 = bx1[t1];
    float cc0 = bx2[t0], cc1 = bx2[t1];
    float u0 = 0.f, u1 = 0.f;
    size_t lbase = (size_t)b * NITEMS;
    for (int pos = wslot; pos < cnt; pos += 128) {
        float wgt = swgt[lbase + pos];
        int item = sidx[lbase + pos];
        const float* xr = x + ((size_t)b * NITEMS + item) * 64;
        float xv = xr[lane];
        float p0 = bb0, p1 = bb1;
        for (int k = 0; k < 64; k++) {
            float xk = __shfl(xv, k);
            p0 = fmaf(xk, wx1[k * 128 + t0], p0);
            p1 = fmaf(xk, wx1[k * 128 + t1], p1);
        }
        float h0 = gelu_f(p0), h1 = gelu_f(p1);
        float a0 = cc0, a1 = cc1;
        for (int j = 0; j < 64; j++) {
            float hj = __shfl(h0, j);
            a0 = fmaf(hj, wx2[j * 128 + t0], a0);
            a1 = fmaf(hj, wx2[j * 128 + t1], a1);
        }
        for (int j = 0; j < 64; j++) {
            float hj = __shfl(h1, j);
            a0 = fmaf(hj, wx2[(j + 64) * 128 + t0], a0);
            a1 = fmaf(hj, wx2[(j + 64) * 128 + t1], a1);
        }
        u0 = fmaf(wgt, a0, u0);
        u1 = fmaf(wgt, a1, u1);
    }
    red[wave][t0] = u0;
    red[wave][t1] = u1;
    __syncthreads();
    if (threadIdx.x < 128) {
        float s = red[0][threadIdx.x] + red[1][threadIdx.x] +
                  red[2][threadIdx.x] + red[3][threadIdx.x];
        atomicAdd(&u[b * 128 + threadIdx.x], s);
    }
}

// ---------- kernel 4: z = u@wvp + bvp ; out = gelu(z@wp1+bp1)@wp2 + bp2 ----------
__global__ __launch_bounds__(128) void k4_head(
    const float* __restrict__ u, const float* __restrict__ wvp, const float* __restrict__ bvp,
    const float* __restrict__ wp1, const float* __restrict__ bp1,
    const float* __restrict__ wp2, const float* __restrict__ bp2,
    float* __restrict__ out) {
    __shared__ float ub[128], zb[128], tb[128];
    int b = blockIdx.x, t = threadIdx.x;
    ub[t] = u[b * 128 + t];
    __syncthreads();
    float z = bvp[t];
    for (int j = 0; j < 128; j++) z = fmaf(ub[j], wvp[j * 128 + t], z);
    zb[t] = z;
    __syncthreads();
    float h = bp1[t];
    for (int j = 0; j < 128; j++) h = fmaf(zb[j], wp1[j * 128 + t], h);
    tb[t] = gelu_f(h);
    __syncthreads();
    if (t < 10) {
        float o = bp2[t];
        for (int j = 0; j < 128; j++) o = fmaf(tb[j], wp2[j * 10 + t], o);
        out[b * 10 + t] = o;
    }
}

// ---------- launch ----------
extern "C" void kernel_launch(void* const* d_in, const int* in_sizes, int n_in,
                              void* d_out, int out_size, void* d_ws, size_t ws_size,
                              hipStream_t stream) {
    const float* x_items = (const float*)d_in[0];
    const float* x_query = (const float*)d_in[1];
    const float* wx1 = (const float*)d_in[2];
    const float* bx1 = (const float*)d_in[3];
    const float* wx2 = (const float*)d_in[4];
    const float* bx2 = (const float*)d_in[5];
    const float* wq1 = (const float*)d_in[6];
    const float* bq1 = (const float*)d_in[7];
    const float* wq2 = (const float*)d_in[8];
    const float* bq2 = (const float*)d_in[9];
    const float* wqp = (const float*)d_in[10];
    const float* bqp = (const float*)d_in[11];
    const float* wkp = (const float*)d_in[12];
    // d_in[13] = bkp: dropped (sparsemax shift invariance)
    const float* wvp = (const float*)d_in[14];
    const float* bvp = (const float*)d_in[15];
    const float* wp1 = (const float*)d_in[16];
    const float* bp1 = (const float*)d_in[17];
    const float* wp2 = (const float*)d_in[18];
    const float* bp2 = (const float*)d_in[19];
    float* out = (float*)d_out;

    char* ws = (char*)d_ws;
    float* r_buf        = (float*)(ws);                                   // 32*128*4   = 16 KB
    unsigned short* w1h = (unsigned short*)(ws + 16384);                  // 128*64*2   = 16 KB
    unsigned short* w1l = (unsigned short*)(ws + 32768);                  // 16 KB
    float* scores       = (float*)(ws + 49152);                           // 32*16384*4 = 2 MB
    float* tau          = (float*)(ws + 2146304);                         // 256 B
    float* u            = (float*)(ws + 2146560);                         // 16 KB
    int*   ctr          = (int*)  (ws + 2162944);                         // 256 B
    int*   sidx         = (int*)  (ws + 2163200);                         // 2 MB
    float* swgt         = (float*)(ws + 4260352);                         // 2 MB

    k0_prep<<<33, 128, 0, stream>>>(x_query, wq1, bq1, wq2, bq2, wqp, bqp, wkp,
                                    wx1, wx2, r_buf, w1h, w1l, ctr);
    k1_items<<<(BATCH * NITEMS) / 64, 256, 0, stream>>>(x_items, w1h, w1l, bx1, r_buf, scores);
    k2_tau<<<BATCH, 1024, 0, stream>>>(scores, tau, u, ctr, sidx, swgt);
    k3_support<<<BATCH * 32, 256, 0, stream>>>(ctr, sidx, swgt, x_items,
                                               wx1, bx1, wx2, bx2, u);
    k4_head<<<BATCH, 128, 0, stream>>>(u, wvp, bvp, wp1, bp1, wp2, bp2, out);
}

// Round 4
// 317.438 us; speedup vs baseline: 1.0318x; 1.0318x over previous
//
#include <hip/hip_runtime.h>
#include <hip/hip_bf16.h>
#include <cstdint>

#define BATCH 32
#define NITEMS 16384
#define DEMB 128
#define IDIM 64

typedef short short8 __attribute__((ext_vector_type(8)));
typedef float f32x4 __attribute__((ext_vector_type(4)));

// ---------- helpers ----------
__device__ inline unsigned short f2bf(float f) {
    union { float f; unsigned int u; } v; v.f = f;
    unsigned int u = v.u;
    unsigned int r = (u + 0x7FFFu + ((u >> 16) & 1u)) >> 16;   // RNE, data is finite
    return (unsigned short)r;
}
__device__ inline float bf2f(unsigned short h) {
    union { unsigned int u; float f; } v; v.u = ((unsigned int)h) << 16;
    return v.f;
}

// Exact-erf gelu via A&S 7.1.26 (|erf err| <= 1.5e-7), restructured:
// q = 0.5*(1-erf(|x|/sqrt2)) = P2(t)*exp2(-x^2*log2(e)/2), t = 1/(1+0.32759*|x|/sqrt2)
// gelu = x * (x>0 ? 1-q : q).  2 trans-pipe ops (rcp, exp2) co-issue with fma.
__device__ inline float gelu_f(float x) {
    float y = fabsf(x) * 0.70710678118654752f;
    float t = __builtin_amdgcn_rcpf(fmaf(0.3275911f, y, 1.0f));
    float p = fmaf(0.5307027145f, t, -0.7265760135f);     // a5/2, a4/2
    p = fmaf(p, t, 0.7107068705f);                        // a3/2
    p = fmaf(p, t, -0.142248368f);                        // a2/2
    p = fmaf(p, t, 0.127414796f);                         // a1/2
    p = p * t;
    float e = __builtin_amdgcn_exp2f(x * x * -0.72134752044448171f);
    float q = p * e;                                      // 0.5*erfc(y)
    float phi = (x > 0.f) ? (1.0f - q) : q;
    return x * phi;
}

// ---------- kernel 0: query path -> r[b] ; split-bf16 weight prep ----------
__global__ __launch_bounds__(128) void k0_prep(
    const float* __restrict__ xq, const float* __restrict__ wq1, const float* __restrict__ bq1,
    const float* __restrict__ wq2, const float* __restrict__ bq2,
    const float* __restrict__ wqp, const float* __restrict__ bqp,
    const float* __restrict__ wkp,
    const float* __restrict__ wx1, const float* __restrict__ wx2,
    float* __restrict__ r_out, unsigned short* __restrict__ w1h, unsigned short* __restrict__ w1l) {
    __shared__ float buf1[128], buf2[128], buf3[128], buf4[128];
    int t = threadIdx.x;
    int blk = blockIdx.x;
    if (blk < BATCH) {
        int b = blk;
        float xqv = xq[b];
        buf1[t] = gelu_f(fmaf(xqv, wq1[t], bq1[t]));
        __syncthreads();
        float acc = bq2[t];
        for (int j = 0; j < 128; j++) acc = fmaf(buf1[j], wq2[j * 128 + t], acc);
        buf2[t] = acc;
        __syncthreads();
        acc = bqp[t];
        for (int j = 0; j < 128; j++) acc = fmaf(buf2[j], wqp[j * 128 + t], acc);
        buf3[t] = acc;                       // q[b]
        __syncthreads();
        acc = 0.f;
        for (int i = 0; i < 128; i++) acc = fmaf(wkp[t * 128 + i], buf3[i], acc);
        buf4[t] = acc * 0.08838834764831845f; // qt = (wkp @ q) * 128^-0.5
        __syncthreads();
        acc = 0.f;
        for (int i = 0; i < 128; i++) acc = fmaf(wx2[t * 128 + i], buf4[i], acc);
        r_out[b * 128 + t] = acc;            // r = wx2 @ qt  (score[n] = h1g[n] . r[b] + const)
    } else {
        // wx1 [64][128] -> w1h/w1l [n=128][k=64] bf16 hi/lo split
        for (int idx = t; idx < 64 * 128; idx += 128) {
            int k = idx >> 7, n = idx & 127;
            float v = wx1[idx];
            unsigned short hi = f2bf(v);
            float lo = v - bf2f(hi);
            w1h[n * 64 + k] = hi;
            w1l[n * 64 + k] = f2bf(lo);
        }
    }
}

// ---------- kernel 1: per-item GEMM1 (split-bf16 MFMA) + gelu + score dot ----------
// TRANSPOSED: C = W1 (A, M=128 n-dims) x X^T (B, N=64 items), K=64.
// C rows = h1-dims, C cols = items -> score dot over n-dims is per-lane FMA +
// 2-step quad shuffle (8 DS ops) instead of a 4-step 16-lane butterfly (64).
// 64 items per block, 256 threads = 4 waves; wave owns 32 rows (2 m-tiles).
__global__ __launch_bounds__(256) void k1_items(
    const float* __restrict__ x, const unsigned short* __restrict__ w1h,
    const unsigned short* __restrict__ w1l, const float* __restrict__ bx1,
    const float* __restrict__ r_in, float* __restrict__ scores) {
    __shared__ alignas(16) unsigned short lxh[64 * 72];
    __shared__ alignas(16) unsigned short lxl[64 * 72];
    __shared__ float red[4][64];
    int tid = threadIdx.x;
    int wave = tid >> 6, lane = tid & 63;
    int quad = lane >> 4, l15 = lane & 15;
    int tile = blockIdx.x;
    long item0 = (long)tile * 64;
    int b = tile >> 8;                       // 256 tiles per batch

    // resident A fragments = weights: rows wave*32 + mt*16 + l15, k-contig
    short8 wh[2][2], wl[2][2];               // [s][mt]
    for (int s = 0; s < 2; s++)
        for (int mt = 0; mt < 2; mt++) {
            int off = (wave * 32 + mt * 16 + l15) * 64 + s * 32 + quad * 8;
            wh[s][mt] = *(const short8*)(w1h + off);
            wl[s][mt] = *(const short8*)(w1l + off);
        }
    // per-lane row constants: row = wave*32 + mt*16 + quad*4 + rr
    float bias8[2][4], rv8[2][4];
    for (int mt = 0; mt < 2; mt++)
        for (int rr = 0; rr < 4; rr++) {
            int row = wave * 32 + mt * 16 + quad * 4 + rr;
            bias8[mt][rr] = bx1[row];
            rv8[mt][rr] = r_in[b * 128 + row];
        }

    // stage x tile [64 items x 64 k]: trunc hi/lo bf16 split via v_perm packing
    const float* xg = x + item0 * 64;
    for (int p = 0; p < 4; p++) {
        int idx = tid + p * 256;
        int row = idx >> 4, c4 = (idx & 15) * 4;
        float4 v = *(const float4*)(xg + row * 64 + c4);
        unsigned int ux = __float_as_uint(v.x), uy = __float_as_uint(v.y);
        unsigned int uz = __float_as_uint(v.z), uw = __float_as_uint(v.w);
        unsigned int hi01 = __builtin_amdgcn_perm(uy, ux, 0x07060302u);
        unsigned int hi23 = __builtin_amdgcn_perm(uw, uz, 0x07060302u);
        float lx = v.x - __uint_as_float(ux & 0xFFFF0000u);
        float ly = v.y - __uint_as_float(uy & 0xFFFF0000u);
        float lz = v.z - __uint_as_float(uz & 0xFFFF0000u);
        float lw = v.w - __uint_as_float(uw & 0xFFFF0000u);
        unsigned int lo01 = __builtin_amdgcn_perm(__float_as_uint(ly), __float_as_uint(lx), 0x07060302u);
        unsigned int lo23 = __builtin_amdgcn_perm(__float_as_uint(lw), __float_as_uint(lz), 0x07060302u);
        *(uint2*)(lxh + row * 72 + c4) = make_uint2(hi01, hi23);
        *(uint2*)(lxl + row * 72 + c4) = make_uint2(lo01, lo23);
    }
    __syncthreads();

    // acc init = bias (row-wise constant, folded into MFMA C)
    f32x4 acc[2][4];                         // [mt][nt]
    for (int mt = 0; mt < 2; mt++)
        for (int nt = 0; nt < 4; nt++) {
            f32x4 bi = {bias8[mt][0], bias8[mt][1], bias8[mt][2], bias8[mt][3]};
            acc[mt][nt] = bi;
        }

    for (int s = 0; s < 2; s++) {
        int koff = s * 32 + quad * 8;
        short8 xh[4], xl[4];                 // B fragments: col = nt*16 + l15
        for (int nt = 0; nt < 4; nt++) {
            int rb = (nt * 16 + l15) * 72 + koff;
            xh[nt] = *(const short8*)(lxh + rb);
            xl[nt] = *(const short8*)(lxl + rb);
        }
        for (int mt = 0; mt < 2; mt++)
            for (int nt = 0; nt < 4; nt++) {
                acc[mt][nt] = __builtin_amdgcn_mfma_f32_16x16x32_bf16(wh[s][mt], xl[nt], acc[mt][nt], 0, 0, 0);
                acc[mt][nt] = __builtin_amdgcn_mfma_f32_16x16x32_bf16(wl[s][mt], xh[nt], acc[mt][nt], 0, 0, 0);
                acc[mt][nt] = __builtin_amdgcn_mfma_f32_16x16x32_bf16(wh[s][mt], xh[nt], acc[mt][nt], 0, 0, 0);
            }
    }

    // epilogue: gelu + dot with r over rows (per-lane), reduce over quad axis
    float pr[4] = {0.f, 0.f, 0.f, 0.f};      // per nt -> item nt*16 + l15
    for (int mt = 0; mt < 2; mt++)
        for (int nt = 0; nt < 4; nt++)
            for (int rr = 0; rr < 4; rr++) {
                float g = gelu_f(acc[mt][nt][rr]);
                pr[nt] = fmaf(g, rv8[mt][rr], pr[nt]);
            }
    for (int nt = 0; nt < 4; nt++) {
        pr[nt] += __shfl_xor(pr[nt], 16);
        pr[nt] += __shfl_xor(pr[nt], 32);
    }
    if (quad == 0)
        for (int nt = 0; nt < 4; nt++)
            red[wave][nt * 16 + l15] = pr[nt];
    __syncthreads();
    if (tid < 64)
        scores[item0 + tid] = red[0][tid] + red[1][tid] + red[2][tid] + red[3][tid];
}

// ---------- kernel 2: sparsemax tau per batch (Michelot fixed point, early exit) ----------
// Iteration 0 with tau=-1e30 reproduces the old init (tau=(sum-1)/N) bit-exactly
// (all lanes active -> same summation order; /16384.0f == *(1/16384.0f) exactly).
// Early exit when tau repeats bit-exactly: Michelot's active set shrinks
// monotonically; identical tau -> identical active set -> fixed point reached.
// Uniform branch: every thread computes identical tls/tct from the same LDS.
// (Round-3 note: ballot-compacted support list + balanced k3 measured -11 us
//  vs this slice-based version; ctr atomics + list writes cost more than the
//  Poisson-tail they remove. Keep the slice structure.)
__global__ __launch_bounds__(1024) void k2_tau(const float* __restrict__ scores,
                                               float* __restrict__ tau_out,
                                               float* __restrict__ u) {
    __shared__ float la[2][16], lc[2][16];
    int b = blockIdx.x, t = threadIdx.x;
    int wid = t >> 6, lane = t & 63;
    const float* s = scores + (size_t)b * NITEMS;
    float z[16];
    for (int i = 0; i < 16; i++) z[i] = s[t + i * 1024];
    float tau = -1e30f;
    for (int it = 0; it < 21; it++) {
        int pb = it & 1;
        float ls = 0.f, ct = 0.f;
        for (int i = 0; i < 16; i++) {
            bool a = z[i] > tau;
            ls += a ? z[i] : 0.f;
            ct += a ? 1.f : 0.f;
        }
        for (int off = 32; off; off >>= 1) {
            ls += __shfl_xor(ls, off);
            ct += __shfl_xor(ct, off);
        }
        if (lane == 0) { la[pb][wid] = ls; lc[pb][wid] = ct; }
        __syncthreads();
        float tls = 0.f, tct = 0.f;
        for (int i = 0; i < 16; i++) { tls += la[pb][i]; tct += lc[pb][i]; }
        float ntau = (tls - 1.0f) / tct;     // ct >= 1 always (max > tau)
        if (ntau == tau) break;              // fixed point reached (uniform)
        tau = ntau;
    }
    if (t == 0) tau_out[b] = tau;
    if (t < 128) u[b * 128 + t] = 0.f;
}

// ---------- kernel 3: one wave per support item, fp32 recompute, shfl broadcasts ----------
// NOTE: no fences / tickets here. Round-1 experiment fused k4 behind an
// agent-scope ticket + __threadfence: the per-block L2 writeback/invalidate
// storm (1024 resident blocks) cost +45 us (k3 73->118 us, VALUBusy 3.4%).
// Stream-ordered separate k4 launch is the cheap correct ordering.
__global__ __launch_bounds__(256) void k3_support(
    const float* __restrict__ scores, const float* __restrict__ tau_in,
    const float* __restrict__ x,
    const float* __restrict__ wx1, const float* __restrict__ bx1,
    const float* __restrict__ wx2, const float* __restrict__ bx2,
    float* __restrict__ u) {
    __shared__ float red[4][128];
    int blk = blockIdx.x;
    int b = blk >> 5;                 // 32 blocks per batch
    int sub = blk & 31;
    int wave = threadIdx.x >> 6, lane = threadIdx.x & 63;
    int wslot = sub * 4 + wave;       // 0..127 within batch
    int base = wslot * 128;           // this wave's 128-item slice
    float tau = tau_in[b];
    int t0 = lane, t1 = lane + 64;
    float bb0 = bx1[t0], bb1 = bx1[t1];
    float cc0 = bx2[t0], cc1 = bx2[t1];
    float u0 = 0.f, u1 = 0.f;
    const float* srow = scores + (size_t)b * NITEMS + base;
    for (int half = 0; half < 2; half++) {
        float sv = srow[half * 64 + lane] - tau;
        unsigned long long mask = __ballot(sv > 0.f);
        while (mask) {
            int src = __ffsll((long long)mask) - 1;
            mask &= mask - 1;
            float wgt = __shfl(sv, src);
            int item = base + half * 64 + src;
            const float* xr = x + ((size_t)b * NITEMS + item) * 64;
            float xv = xr[lane];
            float p0 = bb0, p1 = bb1;
            for (int k = 0; k < 64; k++) {
                float xk = __shfl(xv, k);
                p0 = fmaf(xk, wx1[k * 128 + t0], p0);
                p1 = fmaf(xk, wx1[k * 128 + t1], p1);
            }
            float h0 = gelu_f(p0), h1 = gelu_f(p1);
            float a0 = cc0, a1 = cc1;
            for (int j = 0; j < 64; j++) {
                float hj = __shfl(h0, j);
                a0 = fmaf(hj, wx2[j * 128 + t0], a0);
                a1 = fmaf(hj, wx2[j * 128 + t1], a1);
            }
            for (int j = 0; j < 64; j++) {
                float hj = __shfl(h1, j);
                a0 = fmaf(hj, wx2[(j + 64) * 128 + t0], a0);
                a1 = fmaf(hj, wx2[(j + 64) * 128 + t1], a1);
            }
            u0 = fmaf(wgt, a0, u0);
            u1 = fmaf(wgt, a1, u1);
        }
    }
    red[wave][t0] = u0;
    red[wave][t1] = u1;
    __syncthreads();
    if (threadIdx.x < 128) {
        float s = red[0][threadIdx.x] + red[1][threadIdx.x] +
                  red[2][threadIdx.x] + red[3][threadIdx.x];
        atomicAdd(&u[b * 128 + threadIdx.x], s);
    }
}

// ---------- kernel 4: z = u@wvp + bvp ; out = gelu(z@wp1+bp1)@wp2 + bp2 ----------
__global__ __launch_bounds__(128) void k4_head(
    const float* __restrict__ u, const float* __restrict__ wvp, const float* __restrict__ bvp,
    const float* __restrict__ wp1, const float* __restrict__ bp1,
    const float* __restrict__ wp2, const float* __restrict__ bp2,
    float* __restrict__ out) {
    __shared__ float ub[128], zb[128], tb[128];
    int b = blockIdx.x, t = threadIdx.x;
    ub[t] = u[b * 128 + t];
    __syncthreads();
    float z = bvp[t];
    for (int j = 0; j < 128; j++) z = fmaf(ub[j], wvp[j * 128 + t], z);
    zb[t] = z;
    __syncthreads();
    float h = bp1[t];
    for (int j = 0; j < 128; j++) h = fmaf(zb[j], wp1[j * 128 + t], h);
    tb[t] = gelu_f(h);
    __syncthreads();
    if (t < 10) {
        float o = bp2[t];
        for (int j = 0; j < 128; j++) o = fmaf(tb[j], wp2[j * 10 + t], o);
        out[b * 10 + t] = o;
    }
}

// ---------- launch ----------
extern "C" void kernel_launch(void* const* d_in, const int* in_sizes, int n_in,
                              void* d_out, int out_size, void* d_ws, size_t ws_size,
                              hipStream_t stream) {
    const float* x_items = (const float*)d_in[0];
    const float* x_query = (const float*)d_in[1];
    const float* wx1 = (const float*)d_in[2];
    const float* bx1 = (const float*)d_in[3];
    const float* wx2 = (const float*)d_in[4];
    const float* bx2 = (const float*)d_in[5];
    const float* wq1 = (const float*)d_in[6];
    const float* bq1 = (const float*)d_in[7];
    const float* wq2 = (const float*)d_in[8];
    const float* bq2 = (const float*)d_in[9];
    const float* wqp = (const float*)d_in[10];
    const float* bqp = (const float*)d_in[11];
    const float* wkp = (const float*)d_in[12];
    // d_in[13] = bkp: dropped (sparsemax shift invariance)
    const float* wvp = (const float*)d_in[14];
    const float* bvp = (const float*)d_in[15];
    const float* wp1 = (const float*)d_in[16];
    const float* bp1 = (const float*)d_in[17];
    const float* wp2 = (const float*)d_in[18];
    const float* bp2 = (const float*)d_in[19];
    float* out = (float*)d_out;

    char* ws = (char*)d_ws;
    float* r_buf        = (float*)(ws);                                   // 32*128*4   = 16 KB
    unsigned short* w1h = (unsigned short*)(ws + 16384);                  // 128*64*2   = 16 KB
    unsigned short* w1l = (unsigned short*)(ws + 32768);                  // 16 KB
    float* scores       = (float*)(ws + 49152);                           // 32*16384*4 = 2 MB
    float* tau          = (float*)(ws + 49152 + 2097152);                 // 128 B
    float* u            = (float*)(ws + 49152 + 2097152 + 256);           // 16 KB

    k0_prep<<<33, 128, 0, stream>>>(x_query, wq1, bq1, wq2, bq2, wqp, bqp, wkp,
                                    wx1, wx2, r_buf, w1h, w1l);
    k1_items<<<(BATCH * NITEMS) / 64, 256, 0, stream>>>(x_items, w1h, w1l, bx1, r_buf, scores);
    k2_tau<<<BATCH, 1024, 0, stream>>>(scores, tau, u);
    k3_support<<<BATCH * 32, 256, 0, stream>>>(scores, tau, x_items, wx1, bx1, wx2, bx2, u);
    k4_head<<<BATCH, 128, 0, stream>>>(u, wvp, bvp, wp1, bp1, wp2, bp2, out);
}

// Round 5
// 292.456 us; speedup vs baseline: 1.1200x; 1.0854x over previous
//
#include <hip/hip_runtime.h>
#include <hip/hip_bf16.h>
#include <cstdint>

#define BATCH 32
#define NITEMS 16384
#define DEMB 128
#define IDIM 64

typedef short short8 __attribute__((ext_vector_type(8)));
typedef float f32x4 __attribute__((ext_vector_type(4)));

// ---------- helpers ----------
__device__ inline unsigned short f2bf(float f) {
    union { float f; unsigned int u; } v; v.f = f;
    unsigned int u = v.u;
    unsigned int r = (u + 0x7FFFu + ((u >> 16) & 1u)) >> 16;   // RNE, data is finite
    return (unsigned short)r;
}
__device__ inline float bf2f(unsigned short h) {
    union { unsigned int u; float f; } v; v.u = ((unsigned int)h) << 16;
    return v.f;
}

// Exact-erf gelu via A&S 7.1.26 (|erf err| <= 1.5e-7), restructured:
// q = 0.5*(1-erf(|x|/sqrt2)) = P2(t)*exp2(-x^2*log2(e)/2), t = 1/(1+0.32759*|x|/sqrt2)
// gelu = x * (x>0 ? 1-q : q).  2 trans-pipe ops (rcp, exp2) co-issue with fma.
__device__ inline float gelu_f(float x) {
    float y = fabsf(x) * 0.70710678118654752f;
    float t = __builtin_amdgcn_rcpf(fmaf(0.3275911f, y, 1.0f));
    float p = fmaf(0.5307027145f, t, -0.7265760135f);     // a5/2, a4/2
    p = fmaf(p, t, 0.7107068705f);                        // a3/2
    p = fmaf(p, t, -0.142248368f);                        // a2/2
    p = fmaf(p, t, 0.127414796f);                         // a1/2
    p = p * t;
    float e = __builtin_amdgcn_exp2f(x * x * -0.72134752044448171f);
    float q = p * e;                                      // 0.5*erfc(y)
    float phi = (x > 0.f) ? (1.0f - q) : q;
    return x * phi;
}

// ---------- kernel 0: query path -> r[b] ; split-bf16 weight prep ; ctr zero ----------
__global__ __launch_bounds__(128) void k0_prep(
    const float* __restrict__ xq, const float* __restrict__ wq1, const float* __restrict__ bq1,
    const float* __restrict__ wq2, const float* __restrict__ bq2,
    const float* __restrict__ wqp, const float* __restrict__ bqp,
    const float* __restrict__ wkp,
    const float* __restrict__ wx1, const float* __restrict__ wx2,
    float* __restrict__ r_out, unsigned short* __restrict__ w1h, unsigned short* __restrict__ w1l,
    int* __restrict__ ctr) {
    __shared__ float buf1[128], buf2[128], buf3[128], buf4[128];
    int t = threadIdx.x;
    int blk = blockIdx.x;
    if (blk < BATCH) {
        int b = blk;
        float xqv = xq[b];
        buf1[t] = gelu_f(fmaf(xqv, wq1[t], bq1[t]));
        __syncthreads();
        float acc = bq2[t];
        for (int j = 0; j < 128; j++) acc = fmaf(buf1[j], wq2[j * 128 + t], acc);
        buf2[t] = acc;
        __syncthreads();
        acc = bqp[t];
        for (int j = 0; j < 128; j++) acc = fmaf(buf2[j], wqp[j * 128 + t], acc);
        buf3[t] = acc;                       // q[b]
        __syncthreads();
        acc = 0.f;
        for (int i = 0; i < 128; i++) acc = fmaf(wkp[t * 128 + i], buf3[i], acc);
        buf4[t] = acc * 0.08838834764831845f; // qt = (wkp @ q) * 128^-0.5
        __syncthreads();
        acc = 0.f;
        for (int i = 0; i < 128; i++) acc = fmaf(wx2[t * 128 + i], buf4[i], acc);
        r_out[b * 128 + t] = acc;            // r = wx2 @ qt  (score[n] = h1g[n] . r[b] + const)
    } else {
        if (t < BATCH) ctr[t] = 0;           // support-list counters (workspace is poisoned)
        // wx1 [64][128] -> w1h/w1l [n=128][k=64] bf16 hi/lo split
        for (int idx = t; idx < 64 * 128; idx += 128) {
            int k = idx >> 7, n = idx & 127;
            float v = wx1[idx];
            unsigned short hi = f2bf(v);
            float lo = v - bf2f(hi);
            w1h[n * 64 + k] = hi;
            w1l[n * 64 + k] = f2bf(lo);
        }
    }
}

// ---------- kernel 1: per-item GEMM1 (split-bf16 MFMA) + gelu + score dot ----------
// TRANSPOSED: C = W1 (A, M=128 n-dims) x X^T (B, N=64 items), K=64.
// 64 items per block, 256 threads = 4 waves; wave owns 32 rows (2 m-tiles).
__global__ __launch_bounds__(256) void k1_items(
    const float* __restrict__ x, const unsigned short* __restrict__ w1h,
    const unsigned short* __restrict__ w1l, const float* __restrict__ bx1,
    const float* __restrict__ r_in, float* __restrict__ scores) {
    __shared__ alignas(16) unsigned short lxh[64 * 72];
    __shared__ alignas(16) unsigned short lxl[64 * 72];
    __shared__ float red[4][64];
    int tid = threadIdx.x;
    int wave = tid >> 6, lane = tid & 63;
    int quad = lane >> 4, l15 = lane & 15;
    int tile = blockIdx.x;
    long item0 = (long)tile * 64;
    int b = tile >> 8;                       // 256 tiles per batch

    // resident A fragments = weights: rows wave*32 + mt*16 + l15, k-contig
    short8 wh[2][2], wl[2][2];               // [s][mt]
    for (int s = 0; s < 2; s++)
        for (int mt = 0; mt < 2; mt++) {
            int off = (wave * 32 + mt * 16 + l15) * 64 + s * 32 + quad * 8;
            wh[s][mt] = *(const short8*)(w1h + off);
            wl[s][mt] = *(const short8*)(w1l + off);
        }
    // per-lane row constants: row = wave*32 + mt*16 + quad*4 + rr
    float bias8[2][4], rv8[2][4];
    for (int mt = 0; mt < 2; mt++)
        for (int rr = 0; rr < 4; rr++) {
            int row = wave * 32 + mt * 16 + quad * 4 + rr;
            bias8[mt][rr] = bx1[row];
            rv8[mt][rr] = r_in[b * 128 + row];
        }

    // stage x tile [64 items x 64 k]: trunc hi/lo bf16 split via v_perm packing
    const float* xg = x + item0 * 64;
    for (int p = 0; p < 4; p++) {
        int idx = tid + p * 256;
        int row = idx >> 4, c4 = (idx & 15) * 4;
        float4 v = *(const float4*)(xg + row * 64 + c4);
        unsigned int ux = __float_as_uint(v.x), uy = __float_as_uint(v.y);
        unsigned int uz = __float_as_uint(v.z), uw = __float_as_uint(v.w);
        unsigned int hi01 = __builtin_amdgcn_perm(uy, ux, 0x07060302u);
        unsigned int hi23 = __builtin_amdgcn_perm(uw, uz, 0x07060302u);
        float lx = v.x - __uint_as_float(ux & 0xFFFF0000u);
        float ly = v.y - __uint_as_float(uy & 0xFFFF0000u);
        float lz = v.z - __uint_as_float(uz & 0xFFFF0000u);
        float lw = v.w - __uint_as_float(uw & 0xFFFF0000u);
        unsigned int lo01 = __builtin_amdgcn_perm(__float_as_uint(ly), __float_as_uint(lx), 0x07060302u);
        unsigned int lo23 = __builtin_amdgcn_perm(__float_as_uint(lw), __float_as_uint(lz), 0x07060302u);
        *(uint2*)(lxh + row * 72 + c4) = make_uint2(hi01, hi23);
        *(uint2*)(lxl + row * 72 + c4) = make_uint2(lo01, lo23);
    }
    __syncthreads();

    // acc init = bias (row-wise constant, folded into MFMA C)
    f32x4 acc[2][4];                         // [mt][nt]
    for (int mt = 0; mt < 2; mt++)
        for (int nt = 0; nt < 4; nt++) {
            f32x4 bi = {bias8[mt][0], bias8[mt][1], bias8[mt][2], bias8[mt][3]};
            acc[mt][nt] = bi;
        }

    for (int s = 0; s < 2; s++) {
        int koff = s * 32 + quad * 8;
        short8 xh[4], xl[4];                 // B fragments: col = nt*16 + l15
        for (int nt = 0; nt < 4; nt++) {
            int rb = (nt * 16 + l15) * 72 + koff;
            xh[nt] = *(const short8*)(lxh + rb);
            xl[nt] = *(const short8*)(lxl + rb);
        }
        for (int mt = 0; mt < 2; mt++)
            for (int nt = 0; nt < 4; nt++) {
                acc[mt][nt] = __builtin_amdgcn_mfma_f32_16x16x32_bf16(wh[s][mt], xl[nt], acc[mt][nt], 0, 0, 0);
                acc[mt][nt] = __builtin_amdgcn_mfma_f32_16x16x32_bf16(wl[s][mt], xh[nt], acc[mt][nt], 0, 0, 0);
                acc[mt][nt] = __builtin_amdgcn_mfma_f32_16x16x32_bf16(wh[s][mt], xh[nt], acc[mt][nt], 0, 0, 0);
            }
    }

    // epilogue: gelu + dot with r over rows (per-lane), reduce over quad axis
    float pr[4] = {0.f, 0.f, 0.f, 0.f};      // per nt -> item nt*16 + l15
    for (int mt = 0; mt < 2; mt++)
        for (int nt = 0; nt < 4; nt++)
            for (int rr = 0; rr < 4; rr++) {
                float g = gelu_f(acc[mt][nt][rr]);
                pr[nt] = fmaf(g, rv8[mt][rr], pr[nt]);
            }
    for (int nt = 0; nt < 4; nt++) {
        pr[nt] += __shfl_xor(pr[nt], 16);
        pr[nt] += __shfl_xor(pr[nt], 32);
    }
    if (quad == 0)
        for (int nt = 0; nt < 4; nt++)
            red[wave][nt * 16 + l15] = pr[nt];
    __syncthreads();
    if (tid < 64)
        scores[item0 + tid] = red[0][tid] + red[1][tid] + red[2][tid] + red[3][tid];
}

// ---------- kernel 2: sparsemax tau (Michelot, early exit) + cheap support compaction ----------
// Iteration 0 with tau=-1e30 reproduces the classic init bit-exactly; early exit
// at the bit-exact fixed point (uniform branch).
// Compaction: ONE atomic per wave (16/batch), not one per ballot-slot (256/batch --
// R3's version; its ctr serialization was ~+10 us). Wave reserves its total hit
// count once, then writes its hits at ballot-prefix offsets.
__global__ __launch_bounds__(1024) void k2_tau(const float* __restrict__ scores,
                                               float* __restrict__ tau_out,
                                               float* __restrict__ vbuf,
                                               int* __restrict__ ctr,
                                               int* __restrict__ sidx,
                                               float* __restrict__ swgt) {
    __shared__ float la[2][16], lc[2][16];
    int b = blockIdx.x, t = threadIdx.x;
    int wid = t >> 6, lane = t & 63;
    const float* s = scores + (size_t)b * NITEMS;
    float z[16];
    for (int i = 0; i < 16; i++) z[i] = s[t + i * 1024];
    float tau = -1e30f;
    for (int it = 0; it < 21; it++) {
        int pb = it & 1;
        float ls = 0.f, ct = 0.f;
        for (int i = 0; i < 16; i++) {
            bool a = z[i] > tau;
            ls += a ? z[i] : 0.f;
            ct += a ? 1.f : 0.f;
        }
        for (int off = 32; off; off >>= 1) {
            ls += __shfl_xor(ls, off);
            ct += __shfl_xor(ct, off);
        }
        if (lane == 0) { la[pb][wid] = ls; lc[pb][wid] = ct; }
        __syncthreads();
        float tls = 0.f, tct = 0.f;
        for (int i = 0; i < 16; i++) { tls += la[pb][i]; tct += lc[pb][i]; }
        float ntau = (tls - 1.0f) / tct;     // ct >= 1 always (max > tau)
        if (ntau == tau) break;              // fixed point reached (uniform)
        tau = ntau;
    }
    if (t == 0) tau_out[b] = tau;
    if (t < 128) vbuf[b * 128 + t] = 0.f;

    // ---- compaction: support = { z > tau }, weight = z - tau ----
    size_t lbase = (size_t)b * NITEMS;
    unsigned long long m[16];
    int tot = 0;
    for (int i = 0; i < 16; i++) {
        m[i] = __ballot(z[i] > tau);
        tot += (int)__popcll(m[i]);
    }
    int base = 0;
    if (lane == 0 && tot) base = atomicAdd(&ctr[b], tot);
    base = __shfl(base, 0);
    unsigned long long lmask = (1ULL << lane) - 1ULL;
    for (int i = 0; i < 16; i++) {
        if (z[i] > tau) {
            int off = (int)__popcll(m[i] & lmask);
            sidx[lbase + base + off] = t + i * 1024;
            swgt[lbase + base + off] = z[i] - tau;
        }
        base += (int)__popcll(m[i]);
    }
}

// ---------- kernel 3: support MLP via split-bf16 MFMA over 64-item tiles ----------
// Old k3 (shuffle-broadcast, one wave per item) re-read ~96 KB of wx1/wx2 per
// support item from L2 (working set > L1) -> aggregate-BW-bound ~60 us (inferred
// from R1 fence experiment; R3 showed balancing alone doesn't help).
// Here: v[b] = sum_i wgt_i * gelu(x_i @ wx1 + b1)  computed as k1-style GEMM
// tiles (A = W1 fragments resident in regs, B = gathered X tile in LDS), weights
// read ONCE per block. k4 then applies @wx2 + b2 (sparsemax weights sum to 1,
// same identity k4 already uses for bvp).
// No fences / tickets (R1 lesson: +59 us L2 writeback storm).
__global__ __launch_bounds__(256) void k3_support(
    const int* __restrict__ ctr, const int* __restrict__ sidx,
    const float* __restrict__ swgt, const float* __restrict__ x,
    const unsigned short* __restrict__ w1h, const unsigned short* __restrict__ w1l,
    const float* __restrict__ bx1, float* __restrict__ vbuf) {
    __shared__ alignas(16) unsigned short lxh[64 * 72];
    __shared__ alignas(16) unsigned short lxl[64 * 72];
    __shared__ int litem[64];
    int tid = threadIdx.x;
    int wave = tid >> 6, lane = tid & 63;
    int quad = lane >> 4, l15 = lane & 15;
    int blk = blockIdx.x;
    int b = blk >> 3;                        // 8 blocks per batch
    int sub = blk & 7;
    int cnt = ctr[b];
    size_t lbase = (size_t)b * NITEMS;

    // resident A fragments = weights (identical layout to k1)
    short8 wh[2][2], wl[2][2];               // [s][mt]
    for (int s = 0; s < 2; s++)
        for (int mt = 0; mt < 2; mt++) {
            int off = (wave * 32 + mt * 16 + l15) * 64 + s * 32 + quad * 8;
            wh[s][mt] = *(const short8*)(w1h + off);
            wl[s][mt] = *(const short8*)(w1l + off);
        }
    float bias8[2][4];
    for (int mt = 0; mt < 2; mt++)
        for (int rr = 0; rr < 4; rr++)
            bias8[mt][rr] = bx1[wave * 32 + mt * 16 + quad * 4 + rr];

    float vacc[2][4] = {{0.f, 0.f, 0.f, 0.f}, {0.f, 0.f, 0.f, 0.f}};

    int ntiles = (cnt + 63) >> 6;
    for (int tt = sub; tt < ntiles; tt += 8) {
        int tstart = tt * 64;
        __syncthreads();                     // prior tile's LDS reads complete
        if (tid < 64) {
            int pos = tstart + tid;
            litem[tid] = (pos < cnt) ? sidx[lbase + pos] : 0;   // guard: pad rows read item 0
        }
        __syncthreads();
        // gather + split-bf16 stage (same packing as k1, row -> gathered item)
        for (int p = 0; p < 4; p++) {
            int idx = tid + p * 256;
            int row = idx >> 4, c4 = (idx & 15) * 4;
            const float* xr = x + (lbase + (size_t)litem[row]) * 64;
            float4 v = *(const float4*)(xr + c4);
            unsigned int ux = __float_as_uint(v.x), uy = __float_as_uint(v.y);
            unsigned int uz = __float_as_uint(v.z), uw = __float_as_uint(v.w);
            unsigned int hi01 = __builtin_amdgcn_perm(uy, ux, 0x07060302u);
            unsigned int hi23 = __builtin_amdgcn_perm(uw, uz, 0x07060302u);
            float lx = v.x - __uint_as_float(ux & 0xFFFF0000u);
            float ly = v.y - __uint_as_float(uy & 0xFFFF0000u);
            float lz = v.z - __uint_as_float(uz & 0xFFFF0000u);
            float lw = v.w - __uint_as_float(uw & 0xFFFF0000u);
            unsigned int lo01 = __builtin_amdgcn_perm(__float_as_uint(ly), __float_as_uint(lx), 0x07060302u);
            unsigned int lo23 = __builtin_amdgcn_perm(__float_as_uint(lw), __float_as_uint(lz), 0x07060302u);
            *(uint2*)(lxh + row * 72 + c4) = make_uint2(hi01, hi23);
            *(uint2*)(lxl + row * 72 + c4) = make_uint2(lo01, lo23);
        }
        __syncthreads();

        // per-column (item) sparsemax weights; 0 for pad -> contributes exactly 0
        float wv[4];
        for (int nt = 0; nt < 4; nt++) {
            int pos = tstart + nt * 16 + l15;
            wv[nt] = (pos < cnt) ? swgt[lbase + pos] : 0.f;
        }

        f32x4 acc[2][4];
        for (int mt = 0; mt < 2; mt++)
            for (int nt = 0; nt < 4; nt++) {
                f32x4 bi = {bias8[mt][0], bias8[mt][1], bias8[mt][2], bias8[mt][3]};
                acc[mt][nt] = bi;
            }
        for (int s = 0; s < 2; s++) {
            int koff = s * 32 + quad * 8;
            short8 xh[4], xl[4];
            for (int nt = 0; nt < 4; nt++) {
                int rb = (nt * 16 + l15) * 72 + koff;
                xh[nt] = *(const short8*)(lxh + rb);
                xl[nt] = *(const short8*)(lxl + rb);
            }
            for (int mt = 0; mt < 2; mt++)
                for (int nt = 0; nt < 4; nt++) {
                    acc[mt][nt] = __builtin_amdgcn_mfma_f32_16x16x32_bf16(wh[s][mt], xl[nt], acc[mt][nt], 0, 0, 0);
                    acc[mt][nt] = __builtin_amdgcn_mfma_f32_16x16x32_bf16(wl[s][mt], xh[nt], acc[mt][nt], 0, 0, 0);
                    acc[mt][nt] = __builtin_amdgcn_mfma_f32_16x16x32_bf16(wh[s][mt], xh[nt], acc[mt][nt], 0, 0, 0);
                }
        }
        // weighted gelu accumulate: vacc[row] += wgt[col] * gelu(h1[row][col])
        for (int mt = 0; mt < 2; mt++)
            for (int nt = 0; nt < 4; nt++)
                for (int rr = 0; rr < 4; rr++)
                    vacc[mt][rr] = fmaf(wv[nt], gelu_f(acc[mt][nt][rr]), vacc[mt][rr]);
    }

    // reduce over the 16 column-lanes (l15 axis); rows are unique per (wave,quad,mt,rr)
    for (int mt = 0; mt < 2; mt++)
        for (int rr = 0; rr < 4; rr++) {
            float vs = vacc[mt][rr];
            vs += __shfl_xor(vs, 1);
            vs += __shfl_xor(vs, 2);
            vs += __shfl_xor(vs, 4);
            vs += __shfl_xor(vs, 8);
            if (l15 == 0)
                atomicAdd(&vbuf[b * 128 + wave * 32 + mt * 16 + quad * 4 + rr], vs);
        }
}

// ---------- kernel 4: u = v@wx2 + b2 ; z = u@wvp + bvp ; out = gelu(z@wp1+bp1)@wp2 + bp2 ----------
// (sparsemax weights sum to 1 -> sum(wgt)*b2 = b2, same identity as bvp below)
__global__ __launch_bounds__(128) void k4_head(
    const float* __restrict__ v, const float* __restrict__ wx2, const float* __restrict__ bx2,
    const float* __restrict__ wvp, const float* __restrict__ bvp,
    const float* __restrict__ wp1, const float* __restrict__ bp1,
    const float* __restrict__ wp2, const float* __restrict__ bp2,
    float* __restrict__ out) {
    __shared__ float vb[128], ub[128], zb[128], tb[128];
    int b = blockIdx.x, t = threadIdx.x;
    vb[t] = v[b * 128 + t];
    __syncthreads();
    float uacc = bx2[t];
    for (int j = 0; j < 128; j++) uacc = fmaf(vb[j], wx2[j * 128 + t], uacc);
    ub[t] = uacc;
    __syncthreads();
    float z = bvp[t];
    for (int j = 0; j < 128; j++) z = fmaf(ub[j], wvp[j * 128 + t], z);
    zb[t] = z;
    __syncthreads();
    float h = bp1[t];
    for (int j = 0; j < 128; j++) h = fmaf(zb[j], wp1[j * 128 + t], h);
    tb[t] = gelu_f(h);
    __syncthreads();
    if (t < 10) {
        float o = bp2[t];
        for (int j = 0; j < 128; j++) o = fmaf(tb[j], wp2[j * 10 + t], o);
        out[b * 10 + t] = o;
    }
}

// ---------- launch ----------
extern "C" void kernel_launch(void* const* d_in, const int* in_sizes, int n_in,
                              void* d_out, int out_size, void* d_ws, size_t ws_size,
                              hipStream_t stream) {
    const float* x_items = (const float*)d_in[0];
    const float* x_query = (const float*)d_in[1];
    const float* wx1 = (const float*)d_in[2];
    const float* bx1 = (const float*)d_in[3];
    const float* wx2 = (const float*)d_in[4];
    const float* bx2 = (const float*)d_in[5];
    const float* wq1 = (const float*)d_in[6];
    const float* bq1 = (const float*)d_in[7];
    const float* wq2 = (const float*)d_in[8];
    const float* bq2 = (const float*)d_in[9];
    const float* wqp = (const float*)d_in[10];
    const float* bqp = (const float*)d_in[11];
    const float* wkp = (const float*)d_in[12];
    // d_in[13] = bkp: dropped (sparsemax shift invariance)
    const float* wvp = (const float*)d_in[14];
    const float* bvp = (const float*)d_in[15];
    const float* wp1 = (const float*)d_in[16];
    const float* bp1 = (const float*)d_in[17];
    const float* wp2 = (const float*)d_in[18];
    const float* bp2 = (const float*)d_in[19];
    float* out = (float*)d_out;

    char* ws = (char*)d_ws;
    float* r_buf        = (float*)(ws);                                   // 32*128*4   = 16 KB
    unsigned short* w1h = (unsigned short*)(ws + 16384);                  // 128*64*2   = 16 KB
    unsigned short* w1l = (unsigned short*)(ws + 32768);                  // 16 KB
    float* scores       = (float*)(ws + 49152);                           // 32*16384*4 = 2 MB
    float* tau          = (float*)(ws + 2146304);                         // 256 B
    float* vbuf         = (float*)(ws + 2146560);                         // 16 KB
    int*   ctr          = (int*)  (ws + 2162944);                         // 256 B
    int*   sidx         = (int*)  (ws + 2163200);                         // 2 MB
    float* swgt         = (float*)(ws + 4260352);                         // 2 MB

    k0_prep<<<33, 128, 0, stream>>>(x_query, wq1, bq1, wq2, bq2, wqp, bqp, wkp,
                                    wx1, wx2, r_buf, w1h, w1l, ctr);
    k1_items<<<(BATCH * NITEMS) / 64, 256, 0, stream>>>(x_items, w1h, w1l, bx1, r_buf, scores);
    k2_tau<<<BATCH, 1024, 0, stream>>>(scores, tau, vbuf, ctr, sidx, swgt);
    k3_support<<<BATCH * 8, 256, 0, stream>>>(ctr, sidx, swgt, x_items,
                                              w1h, w1l, bx1, vbuf);
    k4_head<<<BATCH, 128, 0, stream>>>(vbuf, wx2, bx2, wvp, bvp, wp1, bp1, wp2, bp2, out);
}